// Round 16
// baseline (2450.177 us; speedup 1.0000x reference)
//
#include <hip/hip_runtime.h>
#include <hip/hip_bf16.h>
#include <math.h>

#define LN   2048
#define IDM  1024
#define NB   8
#define NEG_SLOPE 0.2f
#define LO_SCALE   4096.0f      // 2^12: keeps f16 lo parts out of denormal range
#define LO_INV     (1.0f/4096.0f)

// ---- i8 quantization scales for the PROJ correction (>6-sigma clips) ----
#define SIH (8.0f/127.0f)            // i hi:  |i| <= 8
#define SIL (2.2e-5f)                // i lo:  |ilo| <= 2e-3, 1.4x margin
#define SWH (0.35f/127.0f)           // w hi:  |w| <= 0.35
#define SWL (SIL*SWH/SIH)            // constraint: SIH*SWL == SIL*SWH
#define COMB_PROJ (SIH*SWL)

typedef _Float16 f16x8 __attribute__((ext_vector_type(8)));
typedef float    f32x4 __attribute__((ext_vector_type(4)));
typedef int      i32x4 __attribute__((ext_vector_type(4)));

#define GLDS16(g, l) \
    __builtin_amdgcn_global_load_lds((const __attribute__((address_space(1))) void*)(g), \
                                     (__attribute__((address_space(3))) void*)(l), 16, 0, 0)

__device__ __forceinline__ int q8(float x, float inv_s) {
    int q = (int)__builtin_rintf(x * inv_s);
    return q > 127 ? 127 : (q < -127 ? -127 : q);
}

extern __shared__ char smem[];   // 128 KiB: 2 step-buffers x (A 32K + B 32K)

// ---------------------------------------------------------------------------
// Round-10/14 schedule (best measured) + byte-addressed segment 0.
// 256x256 tile, 8 waves (2M x 4N), ONE barrier per K-step.
// Segment 0 (K2B BYTES per row, 128 B per step): I8C=1 -> i8 data,
//   mfma_i32_16x16x64_i8, i32 acc converted IN PLACE to f32 * corrScale at the
//   boundary.  I8C=0 -> f16 data, mfma f16, acc *= corrScale (= LO_INV).
//   LDS layout byte-identical in both cases (2 slabs x 64 B per row) -> same
//   staging, same zero-conflict swizzle as rounds 7-14.
// Segment 1 (K1 f16, BK=64): mfma_f32_16x16x32_f16 as round 10/14.
// Per step: vmcnt(0); barrier; stageA(s+1); readA+readB0; lgkm; stageB(s+1);
// readB1; 32 MFMA; lgkm; 32 MFMA.
// EPI: 2 = f32 store [M][N] (+z*zsC)
//      3 = f16 transposed per-2048-row-batch store: VT[b][N][2048]
//      4 = f16 store of (acc + E_f32[M][N])  (+z offsets)
//      5 = f32 store of leaky_relu(acc) + E_f32[row&2047][N]  (flat C)
//      6 = fused QK-proj store (N=2048, round-14 format): col<1024 ->
//          Cv=Qcat f16 [M][2048] hi|lo ; col>=1024 -> extraV=Kcat lo|hi
// ---------------------------------------------------------------------------
template<int EPI, int I8C>
__global__ __launch_bounds__(512, 2) void gemm256(
    const _Float16* __restrict__ A1, long long lda1, int K1,
    const _Float16* __restrict__ B1, long long ldb1,
    const signed char* __restrict__ A2B, long long lda2B, int K2B,
    const signed char* __restrict__ B2B, long long ldb2B,
    float corrScale,
    const void* __restrict__ extraV, void* __restrict__ Cv,
    int M, int N,
    long long zsA, long long zsB, long long zsA2B, long long zsB2B,
    long long zsC, long long zsE)
{
    const int tid  = threadIdx.x;

    // bijective XCD swizzle (all launch grids have nwg % 8 == 0)
    const unsigned nx = gridDim.x, ny = gridDim.y;
    const unsigned lid = blockIdx.x + nx * (blockIdx.y + ny * blockIdx.z);
    const unsigned cpx = (nx * ny * gridDim.z) >> 3;
    const unsigned swzid = (lid & 7) * cpx + (lid >> 3);
    const unsigned bx = swzid % nx, rest = swzid / nx;
    const unsigned by = rest % ny;
    const int z  = (int)(rest / ny);
    const int m0 = (int)by * 256, n0 = (int)bx * 256;

    const int lane = tid & 63;
    const int wid  = tid >> 6;
    const int wm   = wid >> 2;        // 0..1  (M half)
    const int wn   = wid & 3;         // 0..3  (N quarter)

    // staging: dest row = tid>>2, dest slot = tid&3 (linear dest);
    // source byte-col inverse-swizzled with key (destrow>>1)&3 = (tid>>3)&3
    const int sxB  = ((tid & 3) ^ ((tid >> 3) & 3)) << 4;   // bytes

    const int NT2 = K2B >> 7;         // segment-0 steps (128 B each)
    const int NT  = NT2 + (K1 >> 6);  // + f16 steps (64 f16 = 128 B each)

    const char* A1z = (const char*)(A1 + (size_t)z * zsA);
    const char* B1z = (const char*)(B1 + (size_t)z * zsB);
    const char* A2z = (K2B > 0) ? ((const char*)A2B + (size_t)z * zsA2B) : A1z;
    const char* B2z = (K2B > 0) ? ((const char*)B2B + (size_t)z * zsB2B) : B1z;
    const long long ldA1B = lda1 * 2, ldB1B = ldb1 * 2;  // byte strides

    // stage one 128-row half-tile (2 slabs of 64 B) of step st. BYTE addressing.
    auto stageH = [&](int st, int hh) {
        if (st >= NT) return;
        const char* P; long long ldB; long long off;
        if (st < NT2) { P = (hh < 2) ? A2z : B2z; ldB = (hh < 2) ? lda2B : ldb2B; off = (long long)st << 7; }
        else          { P = (hh < 2) ? A1z : B1z; ldB = (hh < 2) ? ldA1B : ldB1B; off = (long long)(st - NT2) << 7; }
        const int row0 = ((hh < 2) ? m0 : n0) + (hh & 1) * 128 + (tid >> 2);
        char* dst = smem + (size_t)(st & 1) * 65536 + ((hh >= 2) ? 32768 : 0)
                         + (hh & 1) * 16384 + tid * 16;
        const char* src = P + (size_t)row0 * ldB + off + sxB;
        GLDS16(src, dst);              // slab 0
        GLDS16(src + 64, dst + 8192);  // slab 1
    };

    const int fr   = lane & 15;
    const int ks4  = (((lane >> 4) ^ ((lane >> 1) & 3)) << 4);  // swizzled byte slot
    const int brow = (wn & 1) * 64 + fr;                        // B row base within half

    // acc storage shared between i8 (i32) and f16 (f32) segments (in-place convert)
    i32x4 acc[8][4] = {};
    #define FACC(i, j) (*reinterpret_cast<f32x4*>(&acc[i][j]))

    f16x8 aF[2][4][2];  f16x8 bF0[2][2];  f16x8 bF1[2][2];
    i32x4 aI[2][4][2];  i32x4 bI0[2][2];  i32x4 bI1[2][2];

    auto readA2 = [&](const char* bufA) {
        #pragma unroll
        for (int mh = 0; mh < 2; ++mh)
            #pragma unroll
            for (int mf = 0; mf < 4; ++mf)
                #pragma unroll
                for (int sl = 0; sl < 2; ++sl)
                    aF[mh][mf][sl] = *(const f16x8*)(bufA + sl * 8192 + ((mh * 4 + mf) * 16 + fr) * 64 + ks4);
    };
    auto readB0 = [&](const char* bufB) {
        #pragma unroll
        for (int nf = 0; nf < 2; ++nf)
            #pragma unroll
            for (int sl = 0; sl < 2; ++sl)
                bF0[nf][sl] = *(const f16x8*)(bufB + sl * 8192 + (brow + nf * 16) * 64 + ks4);
    };
    auto readB1 = [&](const char* bufB) {
        #pragma unroll
        for (int nf = 0; nf < 2; ++nf)
            #pragma unroll
            for (int sl = 0; sl < 2; ++sl)
                bF1[nf][sl] = *(const f16x8*)(bufB + sl * 8192 + (brow + (2 + nf) * 16) * 64 + ks4);
    };
    auto readA2i = [&](const char* bufA) {
        #pragma unroll
        for (int mh = 0; mh < 2; ++mh)
            #pragma unroll
            for (int mf = 0; mf < 4; ++mf)
                #pragma unroll
                for (int sl = 0; sl < 2; ++sl)
                    aI[mh][mf][sl] = *(const i32x4*)(bufA + sl * 8192 + ((mh * 4 + mf) * 16 + fr) * 64 + ks4);
    };
    auto readB0i = [&](const char* bufB) {
        #pragma unroll
        for (int nf = 0; nf < 2; ++nf)
            #pragma unroll
            for (int sl = 0; sl < 2; ++sl)
                bI0[nf][sl] = *(const i32x4*)(bufB + sl * 8192 + (brow + nf * 16) * 64 + ks4);
    };
    auto readB1i = [&](const char* bufB) {
        #pragma unroll
        for (int nf = 0; nf < 2; ++nf)
            #pragma unroll
            for (int sl = 0; sl < 2; ++sl)
                bI1[nf][sl] = *(const i32x4*)(bufB + sl * 8192 + (brow + (2 + nf) * 16) * 64 + ks4);
    };
    auto mmaN = [&](int nh) {
        __builtin_amdgcn_s_setprio(1);
        #pragma unroll
        for (int mh = 0; mh < 2; ++mh)
            #pragma unroll
            for (int mf = 0; mf < 4; ++mf)
                #pragma unroll
                for (int nf = 0; nf < 2; ++nf)
                    #pragma unroll
                    for (int sl = 0; sl < 2; ++sl)
                        FACC(mh * 4 + mf, nh * 2 + nf) = __builtin_amdgcn_mfma_f32_16x16x32_f16(
                            aF[mh][mf][sl], (nh == 0) ? bF0[nf][sl] : bF1[nf][sl],
                            FACC(mh * 4 + mf, nh * 2 + nf), 0, 0, 0);
        __builtin_amdgcn_s_setprio(0);
    };
    auto mmaN8 = [&](int nh) {
        __builtin_amdgcn_s_setprio(1);
        #pragma unroll
        for (int mh = 0; mh < 2; ++mh)
            #pragma unroll
            for (int mf = 0; mf < 4; ++mf)
                #pragma unroll
                for (int nf = 0; nf < 2; ++nf)
                    #pragma unroll
                    for (int sl = 0; sl < 2; ++sl)
                        acc[mh * 4 + mf][nh * 2 + nf] = __builtin_amdgcn_mfma_i32_16x16x64_i8(
                            aI[mh][mf][sl], (nh == 0) ? bI0[nf][sl] : bI1[nf][sl],
                            acc[mh * 4 + mf][nh * 2 + nf], 0, 0, 0);
        __builtin_amdgcn_s_setprio(0);
    };

    // prologue: stage step 0
    stageH(0, 0); stageH(0, 1); stageH(0, 2); stageH(0, 3);

    #pragma unroll 1
    for (int s = 0; s < NT; ++s) {
        const char* base = smem + (size_t)(s & 1) * 65536;
        const char* bufA = base + wm * 16384;
        const char* bufB = base + 32768 + (wn >> 1) * 16384;

        asm volatile("s_waitcnt vmcnt(0)" ::: "memory");   // step s fully landed
        __builtin_amdgcn_s_barrier();                      // the ONLY barrier per step
        __builtin_amdgcn_sched_barrier(0);

        if (s < NT2) {
            stageH(s + 1, 0); stageH(s + 1, 1);
            if (I8C) { readA2i(bufA); readB0i(bufB); } else { readA2(bufA); readB0(bufB); }
            asm volatile("s_waitcnt lgkmcnt(0)" ::: "memory");
            __builtin_amdgcn_sched_barrier(0);
            stageH(s + 1, 2); stageH(s + 1, 3);
            if (I8C) { readB1i(bufB); mmaN8(0); } else { readB1(bufB); mmaN(0); }
            asm volatile("s_waitcnt lgkmcnt(0)" ::: "memory");
            __builtin_amdgcn_sched_barrier(0);
            if (I8C) mmaN8(1); else mmaN(1);
            if (s == NT2 - 1) {   // segment boundary: transform acc in place
                #pragma unroll
                for (int mf = 0; mf < 8; ++mf)
                    #pragma unroll
                    for (int nf = 0; nf < 4; ++nf) {
                        if (I8C) {
                            i32x4 t = acc[mf][nf];
                            FACC(mf, nf) = __builtin_convertvector(t, f32x4) * corrScale;
                        } else {
                            FACC(mf, nf) *= corrScale;
                        }
                    }
            }
        } else {
            stageH(s + 1, 0); stageH(s + 1, 1);
            readA2(bufA); readB0(bufB);
            asm volatile("s_waitcnt lgkmcnt(0)" ::: "memory");
            __builtin_amdgcn_sched_barrier(0);
            stageH(s + 1, 2); stageH(s + 1, 3);
            readB1(bufB);
            mmaN(0);
            asm volatile("s_waitcnt lgkmcnt(0)" ::: "memory");
            __builtin_amdgcn_sched_barrier(0);
            mmaN(1);
        }
    }

    // C/D layout: col = lane&15, row = (lane>>4)*4 + reg
    const int colb = n0 + wn * 64 + (lane & 15);
    const int rowb = m0 + wm * 128 + ((lane >> 4) << 2);

    if (EPI == 2) {
        float* C = (float*)Cv + (size_t)z * zsC;
        #pragma unroll
        for (int mf = 0; mf < 8; ++mf)
            #pragma unroll
            for (int nf = 0; nf < 4; ++nf)
                #pragma unroll
                for (int r = 0; r < 4; ++r)
                    C[(size_t)(rowb + mf * 16 + r) * N + (colb + nf * 16)] = FACC(mf, nf)[r];
    } else if (EPI == 3) {
        _Float16* C = (_Float16*)Cv;   // VT: [batch][N][2048]
        #pragma unroll
        for (int mf = 0; mf < 8; ++mf) {
            const int row = rowb + mf * 16;
            const int bt = row >> 11, ml = row & 2047;
            #pragma unroll
            for (int nf = 0; nf < 4; ++nf) {
                union { _Float16 h[4]; short4 s4; } u;
                #pragma unroll
                for (int r = 0; r < 4; ++r) u.h[r] = (_Float16)FACC(mf, nf)[r];
                *(short4*)&C[(size_t)bt * (size_t)IDM * 2048 + (size_t)(colb + nf * 16) * 2048 + ml] = u.s4;
            }
        }
    } else if (EPI == 4) {
        _Float16* C = (_Float16*)Cv + (size_t)z * zsC;
        const float* E = (const float*)extraV + (size_t)z * zsE;
        #pragma unroll
        for (int mf = 0; mf < 8; ++mf)
            #pragma unroll
            for (int nf = 0; nf < 4; ++nf)
                #pragma unroll
                for (int r = 0; r < 4; ++r) {
                    const size_t idx = (size_t)(rowb + mf * 16 + r) * N + (colb + nf * 16);
                    C[idx] = (_Float16)(FACC(mf, nf)[r] + E[idx]);
                }
    } else if (EPI == 5) {
        float* C = (float*)Cv;
        const float* E = (const float*)extraV;
        #pragma unroll
        for (int mf = 0; mf < 8; ++mf)
            #pragma unroll
            for (int nf = 0; nf < 4; ++nf)
                #pragma unroll
                for (int r = 0; r < 4; ++r) {
                    const int row = rowb + mf * 16 + r;
                    const int col = colb + nf * 16;
                    float v = FACC(mf, nf)[r];
                    v = (v >= 0.f) ? v : NEG_SLOPE * v;
                    C[(size_t)row * N + col] = v + E[(size_t)(row & (LN - 1)) * N + col];
                }
    } else {  // EPI == 6: fused QK projection store (round-14 f16 format)
        _Float16* Cq = (_Float16*)Cv;                       // Qcat [M][2048] hi|lo
        _Float16* Ck = (_Float16*)const_cast<void*>(extraV);// Kcat [M][2048] lo|hi
        #pragma unroll
        for (int mf = 0; mf < 8; ++mf)
            #pragma unroll
            for (int nf = 0; nf < 4; ++nf)
                #pragma unroll
                for (int r = 0; r < 4; ++r) {
                    const int row = rowb + mf * 16 + r;
                    const int col = colb + nf * 16;        // 0..2047
                    float v = FACC(mf, nf)[r];
                    _Float16 h = (_Float16)v;
                    _Float16 l = (_Float16)((v - (float)h) * LO_SCALE);
                    if (col < 1024) {
                        Cq[(size_t)row * 2048 + col]        = h;
                        Cq[(size_t)row * 2048 + 1024 + col] = l;
                    } else {
                        Ck[(size_t)row * 2048 + col]        = h;
                        Ck[(size_t)row * 2048 + col - 1024] = l;
                    }
                }
    }
    #undef FACC
}

// ---------------------------------------------------------------------------
// i split: f32 [M][1024] -> i_hi f16 [M][1024] + iCat8 i8 [M][2048] ([hi/SIH | lo/SIL])
__global__ __launch_bounds__(256) void split_i8k(
    const float* __restrict__ in, _Float16* __restrict__ hi,
    signed char* __restrict__ i8c, long long n4)
{
    long long idx = (long long)blockIdx.x * 256 + threadIdx.x;
    if (idx >= n4) return;
    float4 v = ((const float4*)in)[idx];
    long long row = idx >> 8;
    int c4 = (int)(idx & 255) * 4;
    const float iH = 1.0f / SIH, iL = 1.0f / SIL;
    union { _Float16 h[4]; short4 s4; } hh;
    int ph = 0, pl = 0;
    float f[4] = {v.x, v.y, v.z, v.w};
    #pragma unroll
    for (int j = 0; j < 4; ++j) {
        _Float16 h = (_Float16)f[j];
        hh.h[j] = h;
        float lf = f[j] - (float)h;
        ph |= (q8(f[j], iH) & 255) << (8 * j);
        pl |= (q8(lf,  iL) & 255) << (8 * j);
    }
    *(short4*)&hi[row * 1024 + c4] = hh.s4;
    *(int*)&i8c[row * 2048 + c4]        = ph;
    *(int*)&i8c[row * 2048 + 1024 + c4] = pl;
}

// weight transpose: f32 [1024][1024] -> wT f16 [N][1024] (hi) + w8 i8 [N][2048] ([lo/SWL | hi/SWH])
__global__ __launch_bounds__(256) void split_w8T(
    const float* __restrict__ in, _Float16* __restrict__ wT,
    signed char* __restrict__ w8)
{
    __shared__ float t[32][33];
    const int bx = blockIdx.x * 32, by = blockIdx.y * 32;
    const int tx = threadIdx.x & 31, ty = threadIdx.x >> 5;
    #pragma unroll
    for (int i = 0; i < 32; i += 8)
        t[ty + i][tx] = in[(size_t)(by + ty + i) * 1024 + (bx + tx)];
    __syncthreads();
    const float iWH = 1.0f / SWH, iWL = 1.0f / SWL;
    #pragma unroll
    for (int i = 0; i < 32; i += 8) {
        float f = t[tx][ty + i];               // = in[by+tx][bx+ty+i]
        _Float16 h = (_Float16)f;
        float lf = f - (float)h;
        const size_t n = bx + ty + i, k = by + tx;
        wT[n * 1024 + k] = h;
        w8[n * 2048 + k]        = (signed char)q8(lf, iWL);
        w8[n * 2048 + 1024 + k] = (signed char)q8((float)h, iWH);
    }
}

// plain transpose+convert: in [1024][1024] f32 -> out [N][1024] f16
__global__ __launch_bounds__(256) void transp_f32_f16(
    const float* __restrict__ in, _Float16* __restrict__ out)
{
    __shared__ float t[32][33];
    const int bx = blockIdx.x * 32, by = blockIdx.y * 32;
    const int tx = threadIdx.x & 31, ty = threadIdx.x >> 5;
    #pragma unroll
    for (int i = 0; i < 32; i += 8)
        t[ty + i][tx] = in[(size_t)(by + ty + i) * 1024 + (bx + tx)];
    __syncthreads();
    #pragma unroll
    for (int i = 0; i < 32; i += 8)
        out[(size_t)(bx + ty + i) * 1024 + (by + tx)] = (_Float16)t[tx][ty + i];
}

// row softmax: S f32 [by][2048][2048] -> f16 rows at dst + by*batStr + row*rowStr
__global__ __launch_bounds__(256) void softmax_k(
    const float* __restrict__ S, _Float16* __restrict__ dst,
    long long rowStr, long long batStr)
{
    const int tid = threadIdx.x;
    const float* row = S + (size_t)blockIdx.y * LN * LN + (size_t)blockIdx.x * LN;
    _Float16* orow = dst + (size_t)blockIdx.y * batStr + (size_t)blockIdx.x * rowStr;

    float4 v0 = *(const float4*)&row[tid * 4];
    float4 v1 = *(const float4*)&row[1024 + tid * 4];

    float m = fmaxf(fmaxf(fmaxf(v0.x, v0.y), fmaxf(v0.z, v0.w)),
                    fmaxf(fmaxf(v1.x, v1.y), fmaxf(v1.z, v1.w)));
    #pragma unroll
    for (int off = 32; off > 0; off >>= 1) m = fmaxf(m, __shfl_xor(m, off));

    __shared__ float red[8];
    if ((tid & 63) == 0) red[tid >> 6] = m;
    __syncthreads();
    m = fmaxf(fmaxf(red[0], red[1]), fmaxf(red[2], red[3]));

    float e[8];
    e[0] = __expf(v0.x - m); e[1] = __expf(v0.y - m);
    e[2] = __expf(v0.z - m); e[3] = __expf(v0.w - m);
    e[4] = __expf(v1.x - m); e[5] = __expf(v1.y - m);
    e[6] = __expf(v1.z - m); e[7] = __expf(v1.w - m);
    float s = ((e[0] + e[1]) + (e[2] + e[3])) + ((e[4] + e[5]) + (e[6] + e[7]));
    #pragma unroll
    for (int off = 32; off > 0; off >>= 1) s += __shfl_xor(s, off);
    if ((tid & 63) == 0) red[4 + (tid >> 6)] = s;
    __syncthreads();
    s = (red[4] + red[5]) + (red[6] + red[7]);

    const float inv = 1.0f / s;
    union { _Float16 h[4]; short4 s4; } a, b;
    a.h[0] = (_Float16)(e[0] * inv); a.h[1] = (_Float16)(e[1] * inv);
    a.h[2] = (_Float16)(e[2] * inv); a.h[3] = (_Float16)(e[3] * inv);
    b.h[0] = (_Float16)(e[4] * inv); b.h[1] = (_Float16)(e[5] * inv);
    b.h[2] = (_Float16)(e[6] * inv); b.h[3] = (_Float16)(e[7] * inv);
    *(short4*)&orow[tid * 4] = a.s4;
    *(short4*)&orow[1024 + tid * 4] = b.s4;
}

// ---------------------------------------------------------------------------
extern "C" void kernel_launch(void* const* d_in, const int* in_sizes, int n_in,
                              void* d_out, int out_size, void* d_ws, size_t ws_size,
                              hipStream_t stream)
{
    (void)in_sizes; (void)n_in; (void)out_size;
    const float* i_in  = (const float*)d_in[0];
    const float* k_w   = (const float*)d_in[1];
    const float* q_w   = (const float*)d_in[2];
    const float* v_w   = (const float*)d_in[3];
    const float* mlp_w = (const float*)d_in[4];
    const float* bias  = (const float*)d_in[5];
    float* out = (float*)d_out;

    (void)hipFuncSetAttribute((const void*)gemm256<2,0>, hipFuncAttributeMaxDynamicSharedMemorySize, 131072);
    (void)hipFuncSetAttribute((const void*)gemm256<3,0>, hipFuncAttributeMaxDynamicSharedMemorySize, 131072);
    (void)hipFuncSetAttribute((const void*)gemm256<4,0>, hipFuncAttributeMaxDynamicSharedMemorySize, 131072);
    (void)hipFuncSetAttribute((const void*)gemm256<5,0>, hipFuncAttributeMaxDynamicSharedMemorySize, 131072);
    (void)hipFuncSetAttribute((const void*)gemm256<6,1>, hipFuncAttributeMaxDynamicSharedMemorySize, 131072);

    char* ws = (char*)d_ws;
    const dim3 blk512(512);
    const dim3 blk256(256);
    const dim3 tgrid(32, 32);
    const size_t LDSB = 131072;

    const size_t MiB = 1ull << 20;
    const long long L2048 = 2048, L1024 = 1024;

    if (ws_size >= 236 * MiB) {
        // layout (236 MiB):
        //  [0,32)    i_hi   f16 [16384][1024]   } dead after V-proj;
        //  [32,64)   iCat8  i8  [16384][2048]   } sc f32 aliases [0,64)
        //  [64,128)  Qcat   f16 [16384][2048] hi|lo   (ret aliases)
        //  [128,192) Kcat   f16 [16384][2048] lo|hi   (att aliases)
        //  [192,224) VT     f16 [8][1024][2048]
        //  [224,228) qkT f16 [2048][1024] ; [228,232) qkC8 i8 [2048][2048]
        //  [232,234) vT ; [234,236) mlpT
        _Float16*    i_hi  = (_Float16*)(ws);
        signed char* iCat8 = (signed char*)(ws + 32 * MiB);
        _Float16*    Qcat  = (_Float16*)(ws + 64 * MiB);
        _Float16*    Kcat  = (_Float16*)(ws + 128 * MiB);
        _Float16*    VT    = (_Float16*)(ws + 192 * MiB);
        _Float16*    qkT   = (_Float16*)(ws + 224 * MiB);
        signed char* qkC8  = (signed char*)(ws + 228 * MiB);
        _Float16*    vT    = (_Float16*)(ws + 232 * MiB);
        _Float16*    mlpT  = (_Float16*)(ws + 234 * MiB);
        float*       sc    = (float*)(ws);           // aliases [0,64)
        _Float16*    attA  = Kcat;
        _Float16*    ret   = Qcat;

        split_i8k<<<dim3(16384), blk256, 0, stream>>>(i_in, i_hi, iCat8, (long long)NB * LN * IDM / 4);
        split_w8T<<<tgrid, blk256, 0, stream>>>(q_w, qkT, qkC8);
        split_w8T<<<tgrid, blk256, 0, stream>>>(k_w, qkT + (size_t)1024 * 1024, qkC8 + (size_t)1024 * 2048);
        transp_f32_f16<<<tgrid, blk256, 0, stream>>>(v_w, vT);
        transp_f32_f16<<<tgrid, blk256, 0, stream>>>(mlp_w, mlpT);

        // fused Q+K projection: i8 corr (2048 B/row) + f16 main (K1=1024)
        gemm256<6,1><<<dim3(8, 64), blk512, LDSB, stream>>>(
            i_hi, L1024, 1024, qkT, L1024,
            iCat8, 2048, 2048, qkC8, 2048, COMB_PROJ,
            Kcat, Qcat, NB * LN, 2048, 0, 0, 0, 0, 0, 0);
        // V projection (f16 only) -> VT transposed
        gemm256<3,0><<<dim3(4, 64), blk512, LDSB, stream>>>(
            i_hi, L1024, 1024, vT, L1024,
            nullptr, 0, 0, nullptr, 0, 0.f,
            nullptr, VT, NB * LN, 1024, 0, 0, 0, 0, 0, 0);
        // i_hi/iCat8 now dead; sc aliases them.

        for (int c = 0; c < 2; ++c) {
            const size_t coff = (size_t)c * 4 * LN * 2048;   // f16 elems
            gemm256<2,0><<<dim3(8, 8, 4), blk512, LDSB, stream>>>(
                Qcat + coff, L2048, 1024, Kcat + coff + 1024, L2048,
                (const signed char*)(Qcat + coff), 4096, 4096,
                (const signed char*)(Kcat + coff), 4096, LO_INV,
                nullptr, sc, LN, LN,
                (long long)LN * 2048, (long long)LN * 2048,
                (long long)LN * 4096, (long long)LN * 4096,
                (long long)LN * LN, 0);
            softmax_k<<<dim3(LN, 4), blk256, 0, stream>>>(
                sc, attA + (size_t)c * 4 * LN * LN, L2048, (long long)LN * LN);
        }
        // PV for all 8 batches in ONE dispatch
        gemm256<4,0><<<dim3(4, 8, 8), blk512, LDSB, stream>>>(
            attA, L2048, 2048, VT, L2048,
            nullptr, 0, 0, nullptr, 0, 0.f,
            i_in, ret, LN, IDM,
            (long long)LN * LN, (long long)IDM * LN, 0, 0,
            (long long)LN * IDM, (long long)LN * IDM);
        gemm256<5,0><<<dim3(4, 64), blk512, LDSB, stream>>>(
            ret, L1024, 1024, mlpT, L1024,
            nullptr, 0, 0, nullptr, 0, 0.f,
            bias, out, NB * LN, 1024, 0, 0, 0, 0, 0, 0);
    } else {
        // -------- small path (~56 MiB), per batch --------
        _Float16*    qkT   = (_Float16*)(ws);                 // 4 MiB
        signed char* qkC8  = (signed char*)(ws + 4 * MiB);    // 4 MiB
        _Float16*    vT    = (_Float16*)(ws + 8 * MiB);
        _Float16*    mlpT  = (_Float16*)(ws + 10 * MiB);
        _Float16*    i_hi  = (_Float16*)(ws + 12 * MiB);      // 4 MiB
        signed char* iCat8 = (signed char*)(ws + 16 * MiB);   // 4 MiB
        _Float16*    Qcat  = (_Float16*)(ws + 20 * MiB);      // 8 MiB
        _Float16*    Kcat  = (_Float16*)(ws + 28 * MiB);      // 8 MiB (att alias)
        _Float16*    VTb   = (_Float16*)(ws + 36 * MiB);      // 4 MiB
        float*       sc    = (float*)(ws + 40 * MiB);         // 16 MiB
        _Float16*    ret   = Qcat;

        split_w8T<<<tgrid, blk256, 0, stream>>>(q_w, qkT, qkC8);
        split_w8T<<<tgrid, blk256, 0, stream>>>(k_w, qkT + (size_t)1024 * 1024, qkC8 + (size_t)1024 * 2048);
        transp_f32_f16<<<tgrid, blk256, 0, stream>>>(v_w, vT);
        transp_f32_f16<<<tgrid, blk256, 0, stream>>>(mlp_w, mlpT);

        for (int b = 0; b < NB; ++b) {
            const size_t boff = (size_t)b * LN * IDM;
            split_i8k<<<dim3(2048), blk256, 0, stream>>>(i_in + boff, i_hi, iCat8, (long long)LN * IDM / 4);
            gemm256<6,1><<<dim3(8, 8), blk512, LDSB, stream>>>(
                i_hi, L1024, 1024, qkT, L1024,
                iCat8, 2048, 2048, qkC8, 2048, COMB_PROJ,
                Kcat, Qcat, LN, 2048, 0, 0, 0, 0, 0, 0);
            gemm256<3,0><<<dim3(4, 8), blk512, LDSB, stream>>>(
                i_hi, L1024, 1024, vT, L1024,
                nullptr, 0, 0, nullptr, 0, 0.f,
                nullptr, VTb, LN, 1024, 0, 0, 0, 0, 0, 0);
            gemm256<2,0><<<dim3(8, 8), blk512, LDSB, stream>>>(
                Qcat, L2048, 1024, Kcat + 1024, L2048,
                (const signed char*)Qcat, 4096, 4096,
                (const signed char*)Kcat, 4096, LO_INV,
                nullptr, sc, LN, LN, 0, 0, 0, 0, 0, 0);
            softmax_k<<<dim3(LN, 1), blk256, 0, stream>>>(sc, Kcat, L2048, 0);
            gemm256<4,0><<<dim3(4, 8), blk512, LDSB, stream>>>(
                Kcat, L2048, 2048, VTb, L2048,
                nullptr, 0, 0, nullptr, 0, 0.f,
                i_in + boff, ret, LN, IDM, 0, 0, 0, 0, 0, 0);
            gemm256<5,0><<<dim3(4, 8), blk512, LDSB, stream>>>(
                ret, L1024, 1024, mlpT, L1024,
                nullptr, 0, 0, nullptr, 0, 0.f,
                bias, out + boff, LN, 1024, 0, 0, 0, 0, 0, 0);
        }
    }
}

// Round 17
// 610.034 us; speedup vs baseline: 4.0165x; 4.0165x over previous
//
#include <hip/hip_runtime.h>
#include <hip/hip_bf16.h>
#include <math.h>

#define LN   2048
#define IDM  1024
#define NB   8
#define NEG_SLOPE 0.2f
#define LO_SCALE   4096.0f      // 2^12: keeps lo parts out of f16 denormal range
#define LO_INV     (1.0f/4096.0f)

typedef _Float16 f16x8 __attribute__((ext_vector_type(8)));
typedef float    f32x4 __attribute__((ext_vector_type(4)));

#define GLDS16(g, l) \
    __builtin_amdgcn_global_load_lds((const __attribute__((address_space(1))) void*)(g), \
                                     (__attribute__((address_space(3))) void*)(l), 16, 0, 0)

extern __shared__ char smem[];   // 128 KiB: 2 step-buffers x (A 32K + B 32K)

// ---------------------------------------------------------------------------
// FINAL KERNEL = ROUND-10/14 STRUCTURE (best measured: 611 us total,
// fused-QK 203 us = 1015 TF, zero bank conflicts, absmax 0.0625).
// 256x256 tile, BK=64, 8 waves (2M x 4N), ONE barrier per K-step.
// Per step (per wave): stage A | read aF(16)+bF0(4) | lgkm | stage B, issue
// bF1(4) | 32 MFMA on bF0 (covers bF1 latency) | lgkm | 32 MFMA on bF1.
// No intra-step barriers: regions read the same landed buffer (the step-entry
// barrier alone covers the double-buffer write-after-read hazard), so waves
// desync and one wave's ds_reads overlap other waves' MFMA clusters.
// 16x16x32 MFMA: its 16-row ds_read pattern is the only conflict-free one
// under this staging layout (32x32's 32-row pattern = 4-way, round 13).
// LDS slot-swizzle key (row>>1)&3, inverse-applied on the global source.
// 2-segment K (Ozaki split-f16): (A2,B2,K2) correction first, then
// acc *= 2^-12, then (A1,B1,K1) main.
// A: [M][K] f16 rows (stride lda).  B: [N][K] f16 rows (stride ldb).
// EPI: 0 = split store hi|lo  (C f16 [M][2N]) ; 1 = split store lo|hi
//      2 = f32 store [M][N]
//      3 = f16 transposed per-2048-row-batch store: VT[b][N][2048]
//      4 = f16 store of (acc + E_f32[M][N])
//      5 = f32 store of leaky_relu(acc) + E_f32[row&2047][N]
//      6 = fused QK-proj store (N=2048): col<1024 -> Cv=Qcat hi|lo,
//          col>=1024 -> extraV=Kcat lo|hi (both [M][2048])
// ---------------------------------------------------------------------------
template<int EPI>
__global__ __launch_bounds__(512, 2) void gemm256(
    const _Float16* __restrict__ A1, long long lda1, int K1,
    const _Float16* __restrict__ B1, long long ldb1,
    const _Float16* __restrict__ A2, long long lda2, int K2,
    const _Float16* __restrict__ B2, long long ldb2,
    const void* __restrict__ extraV, void* __restrict__ Cv,
    int M, int N,
    long long zsA, long long zsB, long long zsC, long long zsE)
{
    const int tid  = threadIdx.x;

    // bijective XCD swizzle (all launch grids have nwg % 8 == 0)
    const unsigned nx = gridDim.x, ny = gridDim.y;
    const unsigned lid = blockIdx.x + nx * (blockIdx.y + ny * blockIdx.z);
    const unsigned cpx = (nx * ny * gridDim.z) >> 3;
    const unsigned swzid = (lid & 7) * cpx + (lid >> 3);
    const unsigned bx = swzid % nx, rest = swzid / nx;
    const unsigned by = rest % ny;
    const int z  = (int)(rest / ny);
    const int m0 = (int)by * 256, n0 = (int)bx * 256;

    const int lane = tid & 63;
    const int wid  = tid >> 6;
    const int wm   = wid >> 2;        // 0..1  (M half)
    const int wn   = wid & 3;         // 0..3  (N quarter)

    // staging: dest row = tid>>2 (0..127), dest slot = tid&3 (linear dest);
    // source col inverse-swizzled with key (destrow>>1)&3 = (tid>>3)&3
    const int sx   = ((tid & 3) ^ ((tid >> 3) & 3)) << 3;   // f16 units

    const int NT2 = K2 >> 6;
    const int NT  = NT2 + (K1 >> 6);

    const _Float16* A1z = A1 + (size_t)z * zsA;
    const _Float16* B1z = B1 + (size_t)z * zsB;
    const _Float16* A2z = (K2 > 0) ? A2 + (size_t)z * zsA : A1z;
    const _Float16* B2z = (K2 > 0) ? B2 + (size_t)z * zsB : B1z;

    // stage one 128-row half-tile (2 slabs of 32 k) of step st.
    // hh: 0 = A rows 0-127, 1 = A rows 128-255, 2 = B rows 0-127, 3 = B rows 128-255
    auto stageH = [&](int st, int hh) {
        if (st >= NT) return;
        const _Float16* P; long long ld; int kk;
        if (st < NT2) { P = (hh < 2) ? A2z : B2z; ld = (hh < 2) ? lda2 : ldb2; kk = st << 6; }
        else          { P = (hh < 2) ? A1z : B1z; ld = (hh < 2) ? lda1 : ldb1; kk = (st - NT2) << 6; }
        const int row0 = ((hh < 2) ? m0 : n0) + (hh & 1) * 128 + (tid >> 2);
        char* dst = smem + (size_t)(st & 1) * 65536 + ((hh >= 2) ? 32768 : 0)
                         + (hh & 1) * 16384 + tid * 16;
        const _Float16* src = P + (size_t)row0 * ld + kk + sx;
        GLDS16(src, dst);              // slab 0 (k 0-31)
        GLDS16(src + 32, dst + 8192);  // slab 1 (k 32-63)
    };

    const int fr   = lane & 15;
    const int ks4  = (((lane >> 4) ^ ((lane >> 1) & 3)) << 4);  // swizzled byte slot
    const int brow = (wn & 1) * 64 + fr;                        // B row base within half

    f32x4 acc[8][4] = {};
    f16x8 aF[2][4][2];       // both m-halves cached (64 VGPR)
    f16x8 bF0[2][2];         // B quadrant 0 (16 VGPR)
    f16x8 bF1[2][2];         // B quadrant 1 (16 VGPR)

    auto readA2 = [&](const char* bufA) {
        #pragma unroll
        for (int mh = 0; mh < 2; ++mh)
            #pragma unroll
            for (int mf = 0; mf < 4; ++mf)
                #pragma unroll
                for (int sl = 0; sl < 2; ++sl)
                    aF[mh][mf][sl] = *(const f16x8*)(bufA + sl * 8192 + ((mh * 4 + mf) * 16 + fr) * 64 + ks4);
    };
    auto readB0 = [&](const char* bufB) {
        #pragma unroll
        for (int nf = 0; nf < 2; ++nf)
            #pragma unroll
            for (int sl = 0; sl < 2; ++sl)
                bF0[nf][sl] = *(const f16x8*)(bufB + sl * 8192 + (brow + nf * 16) * 64 + ks4);
    };
    auto readB1 = [&](const char* bufB) {
        #pragma unroll
        for (int nf = 0; nf < 2; ++nf)
            #pragma unroll
            for (int sl = 0; sl < 2; ++sl)
                bF1[nf][sl] = *(const f16x8*)(bufB + sl * 8192 + (brow + (2 + nf) * 16) * 64 + ks4);
    };
    auto mmaN = [&](int nh) {   // nh=0 uses bF0 -> acc[.][0..1]; nh=1 uses bF1 -> acc[.][2..3]
        __builtin_amdgcn_s_setprio(1);
        #pragma unroll
        for (int mh = 0; mh < 2; ++mh)
            #pragma unroll
            for (int mf = 0; mf < 4; ++mf)
                #pragma unroll
                for (int nf = 0; nf < 2; ++nf)
                    #pragma unroll
                    for (int sl = 0; sl < 2; ++sl)
                        acc[mh * 4 + mf][nh * 2 + nf] = __builtin_amdgcn_mfma_f32_16x16x32_f16(
                            aF[mh][mf][sl], (nh == 0) ? bF0[nf][sl] : bF1[nf][sl],
                            acc[mh * 4 + mf][nh * 2 + nf], 0, 0, 0);
        __builtin_amdgcn_s_setprio(0);
    };

    // prologue: stage step 0
    stageH(0, 0); stageH(0, 1); stageH(0, 2); stageH(0, 3);

    #pragma unroll 1
    for (int s = 0; s < NT; ++s) {
        const char* base = smem + (size_t)(s & 1) * 65536;
        const char* bufA = base + wm * 16384;
        const char* bufB = base + 32768 + (wn >> 1) * 16384;

        asm volatile("s_waitcnt vmcnt(0)" ::: "memory");   // step s fully landed
        __builtin_amdgcn_s_barrier();                      // the ONLY barrier per step
        __builtin_amdgcn_sched_barrier(0);

        stageH(s + 1, 0); stageH(s + 1, 1);
        readA2(bufA); readB0(bufB);                        // 20 ds_reads
        asm volatile("s_waitcnt lgkmcnt(0)" ::: "memory");
        __builtin_amdgcn_sched_barrier(0);

        stageH(s + 1, 2); stageH(s + 1, 3);
        readB1(bufB);                                      // latency hides under mmaN(0)
        mmaN(0);                                           // 32 MFMA on bF0
        asm volatile("s_waitcnt lgkmcnt(0)" ::: "memory");
        __builtin_amdgcn_sched_barrier(0);
        mmaN(1);                                           // 32 MFMA on bF1

        if (s == NT2 - 1) {
            #pragma unroll
            for (int mf = 0; mf < 8; ++mf)
                #pragma unroll
                for (int nf = 0; nf < 4; ++nf)
                    acc[mf][nf] *= LO_INV;
        }
    }

    // C/D layout: col = lane&15, row = (lane>>4)*4 + reg
    const int colb = n0 + wn * 64 + (lane & 15);
    const int rowb = m0 + wm * 128 + ((lane >> 4) << 2);

    if (EPI == 0 || EPI == 1) {
        _Float16* C = (_Float16*)Cv + (size_t)z * zsC;
        const long long ldc = 2 * (long long)N;
        #pragma unroll
        for (int mf = 0; mf < 8; ++mf)
            #pragma unroll
            for (int nf = 0; nf < 4; ++nf)
                #pragma unroll
                for (int r = 0; r < 4; ++r) {
                    const int row = rowb + mf * 16 + r;
                    const int col = colb + nf * 16;
                    float v = acc[mf][nf][r];
                    _Float16 h = (_Float16)v;
                    _Float16 l = (_Float16)((v - (float)h) * LO_SCALE);
                    if (EPI == 0) {
                        C[(size_t)row * ldc + col]     = h;
                        C[(size_t)row * ldc + N + col] = l;
                    } else {
                        C[(size_t)row * ldc + col]     = l;
                        C[(size_t)row * ldc + N + col] = h;
                    }
                }
    } else if (EPI == 2) {
        float* C = (float*)Cv + (size_t)z * zsC;
        #pragma unroll
        for (int mf = 0; mf < 8; ++mf)
            #pragma unroll
            for (int nf = 0; nf < 4; ++nf)
                #pragma unroll
                for (int r = 0; r < 4; ++r)
                    C[(size_t)(rowb + mf * 16 + r) * N + (colb + nf * 16)] = acc[mf][nf][r];
    } else if (EPI == 3) {
        _Float16* C = (_Float16*)Cv;   // VT: [batch][N][2048]
        #pragma unroll
        for (int mf = 0; mf < 8; ++mf) {
            const int row = rowb + mf * 16;
            const int bt = row >> 11, ml = row & 2047;
            #pragma unroll
            for (int nf = 0; nf < 4; ++nf) {
                union { _Float16 h[4]; short4 s4; } u;
                #pragma unroll
                for (int r = 0; r < 4; ++r) u.h[r] = (_Float16)acc[mf][nf][r];
                *(short4*)&C[(size_t)bt * (size_t)IDM * 2048 + (size_t)(colb + nf * 16) * 2048 + ml] = u.s4;
            }
        }
    } else if (EPI == 4) {
        _Float16* C = (_Float16*)Cv + (size_t)z * zsC;
        const float* E = (const float*)extraV + (size_t)z * zsE;
        #pragma unroll
        for (int mf = 0; mf < 8; ++mf)
            #pragma unroll
            for (int nf = 0; nf < 4; ++nf)
                #pragma unroll
                for (int r = 0; r < 4; ++r) {
                    const size_t idx = (size_t)(rowb + mf * 16 + r) * N + (colb + nf * 16);
                    C[idx] = (_Float16)(acc[mf][nf][r] + E[idx]);
                }
    } else if (EPI == 5) {
        float* C = (float*)Cv;
        const float* E = (const float*)extraV;
        #pragma unroll
        for (int mf = 0; mf < 8; ++mf)
            #pragma unroll
            for (int nf = 0; nf < 4; ++nf)
                #pragma unroll
                for (int r = 0; r < 4; ++r) {
                    const int row = rowb + mf * 16 + r;
                    const int col = colb + nf * 16;
                    float v = acc[mf][nf][r];
                    v = (v >= 0.f) ? v : NEG_SLOPE * v;
                    C[(size_t)row * N + col] = v + E[(size_t)(row & (LN - 1)) * N + col];
                }
    } else {  // EPI == 6: fused QK projection store
        _Float16* Cq = (_Float16*)Cv;                       // Qcat [M][2048] hi|lo
        _Float16* Ck = (_Float16*)const_cast<void*>(extraV);// Kcat [M][2048] lo|hi
        #pragma unroll
        for (int mf = 0; mf < 8; ++mf)
            #pragma unroll
            for (int nf = 0; nf < 4; ++nf)
                #pragma unroll
                for (int r = 0; r < 4; ++r) {
                    const int row = rowb + mf * 16 + r;
                    const int col = colb + nf * 16;        // 0..2047
                    float v = acc[mf][nf][r];
                    _Float16 h = (_Float16)v;
                    _Float16 l = (_Float16)((v - (float)h) * LO_SCALE);
                    if (col < 1024) {
                        Cq[(size_t)row * 2048 + col]        = h;
                        Cq[(size_t)row * 2048 + 1024 + col] = l;
                    } else {
                        Ck[(size_t)row * 2048 + col]        = h;
                        Ck[(size_t)row * 2048 + col - 1024] = l;
                    }
                }
    }
}

// ---------------------------------------------------------------------------
// i split: f32 [M][1024] -> f16 [M][2048]  (hi | lo*2^12)
__global__ __launch_bounds__(256) void split_i_k(
    const float* __restrict__ in, _Float16* __restrict__ out, long long n4)
{
    long long idx = (long long)blockIdx.x * 256 + threadIdx.x;
    if (idx >= n4) return;
    float4 v = ((const float4*)in)[idx];
    long long row = idx >> 8;
    int c4 = (int)(idx & 255) * 4;
    union { _Float16 h[4]; short4 s4; } hi, lo;
    float f0 = v.x; _Float16 h0 = (_Float16)f0; hi.h[0] = h0; lo.h[0] = (_Float16)((f0 - (float)h0) * LO_SCALE);
    float f1 = v.y; _Float16 h1 = (_Float16)f1; hi.h[1] = h1; lo.h[1] = (_Float16)((f1 - (float)h1) * LO_SCALE);
    float f2 = v.z; _Float16 h2 = (_Float16)f2; hi.h[2] = h2; lo.h[2] = (_Float16)((f2 - (float)h2) * LO_SCALE);
    float f3 = v.w; _Float16 h3 = (_Float16)f3; hi.h[3] = h3; lo.h[3] = (_Float16)((f3 - (float)h3) * LO_SCALE);
    *(short4*)&out[row * 2048 + c4]        = hi.s4;
    *(short4*)&out[row * 2048 + 1024 + c4] = lo.s4;
}

// weight transpose+split: in [K=1024][N=1024] f32 -> out [N][2048] (lo*2^12 | hi)
__global__ __launch_bounds__(256) void split_wT_k(
    const float* __restrict__ in, _Float16* __restrict__ out)
{
    __shared__ float t[32][33];
    const int bx = blockIdx.x * 32, by = blockIdx.y * 32;
    const int tx = threadIdx.x & 31, ty = threadIdx.x >> 5;
    #pragma unroll
    for (int i = 0; i < 32; i += 8)
        t[ty + i][tx] = in[(size_t)(by + ty + i) * 1024 + (bx + tx)];
    __syncthreads();
    #pragma unroll
    for (int i = 0; i < 32; i += 8) {
        float f = t[tx][ty + i];
        _Float16 h = (_Float16)f;
        _Float16 l = (_Float16)((f - (float)h) * LO_SCALE);
        const size_t n = bx + ty + i, k = by + tx;
        out[n * 2048 + k]        = l;
        out[n * 2048 + 1024 + k] = h;
    }
}

// plain transpose+convert: in [K=1024][N=1024] f32 -> out [N][1024] f16
__global__ __launch_bounds__(256) void transp_f32_f16(
    const float* __restrict__ in, _Float16* __restrict__ out)
{
    __shared__ float t[32][33];
    const int bx = blockIdx.x * 32, by = blockIdx.y * 32;
    const int tx = threadIdx.x & 31, ty = threadIdx.x >> 5;
    #pragma unroll
    for (int i = 0; i < 32; i += 8)
        t[ty + i][tx] = in[(size_t)(by + ty + i) * 1024 + (bx + tx)];
    __syncthreads();
    #pragma unroll
    for (int i = 0; i < 32; i += 8)
        out[(size_t)(bx + ty + i) * 1024 + (by + tx)] = (_Float16)t[tx][ty + i];
}

// row softmax: S f32 [by][2048][2048] -> f16 rows at dst + by*batStr + row*rowStr
__global__ __launch_bounds__(256) void softmax_k(
    const float* __restrict__ S, _Float16* __restrict__ dst,
    long long rowStr, long long batStr)
{
    const int tid = threadIdx.x;
    const float* row = S + (size_t)blockIdx.y * LN * LN + (size_t)blockIdx.x * LN;
    _Float16* orow = dst + (size_t)blockIdx.y * batStr + (size_t)blockIdx.x * rowStr;

    float4 v0 = *(const float4*)&row[tid * 4];
    float4 v1 = *(const float4*)&row[1024 + tid * 4];

    float m = fmaxf(fmaxf(fmaxf(v0.x, v0.y), fmaxf(v0.z, v0.w)),
                    fmaxf(fmaxf(v1.x, v1.y), fmaxf(v1.z, v1.w)));
    #pragma unroll
    for (int off = 32; off > 0; off >>= 1) m = fmaxf(m, __shfl_xor(m, off));

    __shared__ float red[8];
    if ((tid & 63) == 0) red[tid >> 6] = m;
    __syncthreads();
    m = fmaxf(fmaxf(red[0], red[1]), fmaxf(red[2], red[3]));

    float e[8];
    e[0] = __expf(v0.x - m); e[1] = __expf(v0.y - m);
    e[2] = __expf(v0.z - m); e[3] = __expf(v0.w - m);
    e[4] = __expf(v1.x - m); e[5] = __expf(v1.y - m);
    e[6] = __expf(v1.z - m); e[7] = __expf(v1.w - m);
    float s = ((e[0] + e[1]) + (e[2] + e[3])) + ((e[4] + e[5]) + (e[6] + e[7]));
    #pragma unroll
    for (int off = 32; off > 0; off >>= 1) s += __shfl_xor(s, off);
    if ((tid & 63) == 0) red[4 + (tid >> 6)] = s;
    __syncthreads();
    s = (red[4] + red[5]) + (red[6] + red[7]);

    const float inv = 1.0f / s;
    union { _Float16 h[4]; short4 s4; } a, b;
    a.h[0] = (_Float16)(e[0] * inv); a.h[1] = (_Float16)(e[1] * inv);
    a.h[2] = (_Float16)(e[2] * inv); a.h[3] = (_Float16)(e[3] * inv);
    b.h[0] = (_Float16)(e[4] * inv); b.h[1] = (_Float16)(e[5] * inv);
    b.h[2] = (_Float16)(e[6] * inv); b.h[3] = (_Float16)(e[7] * inv);
    *(short4*)&orow[tid * 4] = a.s4;
    *(short4*)&orow[1024 + tid * 4] = b.s4;
}

// ---------------------------------------------------------------------------
extern "C" void kernel_launch(void* const* d_in, const int* in_sizes, int n_in,
                              void* d_out, int out_size, void* d_ws, size_t ws_size,
                              hipStream_t stream)
{
    (void)in_sizes; (void)n_in; (void)out_size;
    const float* i_in  = (const float*)d_in[0];
    const float* k_w   = (const float*)d_in[1];
    const float* q_w   = (const float*)d_in[2];
    const float* v_w   = (const float*)d_in[3];
    const float* mlp_w = (const float*)d_in[4];
    const float* bias  = (const float*)d_in[5];
    float* out = (float*)d_out;

    (void)hipFuncSetAttribute((const void*)gemm256<2>, hipFuncAttributeMaxDynamicSharedMemorySize, 131072);
    (void)hipFuncSetAttribute((const void*)gemm256<3>, hipFuncAttributeMaxDynamicSharedMemorySize, 131072);
    (void)hipFuncSetAttribute((const void*)gemm256<4>, hipFuncAttributeMaxDynamicSharedMemorySize, 131072);
    (void)hipFuncSetAttribute((const void*)gemm256<5>, hipFuncAttributeMaxDynamicSharedMemorySize, 131072);
    (void)hipFuncSetAttribute((const void*)gemm256<6>, hipFuncAttributeMaxDynamicSharedMemorySize, 131072);

    char* ws = (char*)d_ws;
    const dim3 blk512(512);
    const dim3 blk256(256);
    const dim3 tgrid(32, 32);
    const size_t LDSB = 131072;

    const size_t MiB = 1ull << 20;
    const long long L2048 = 2048, L1024 = 1024, L4096 = 4096;

    if (ws_size >= 236 * MiB) {
        _Float16* Qcat  = (_Float16*)(ws);
        _Float16* Kcat  = (_Float16*)(ws + 64 * MiB);
        _Float16* VT    = (_Float16*)(ws + 128 * MiB);
        _Float16* qCatT = (_Float16*)(ws + 160 * MiB);   // contiguous with kCatT
        _Float16* kCatT = (_Float16*)(ws + 164 * MiB);
        _Float16* vT    = (_Float16*)(ws + 168 * MiB);
        _Float16* mlpT  = (_Float16*)(ws + 170 * MiB);
        _Float16* iCat  = (_Float16*)(ws + 172 * MiB);
        float*    sc    = (float*)(ws + 172 * MiB);     // 4 batches x 16 MiB (aliases iCat)
        _Float16* attA  = Kcat;                          // att written per-chunk AFTER scores read Kcat
        _Float16* ret   = Qcat;                          // dead after scores

        split_i_k<<<dim3(16384), blk256, 0, stream>>>(i_in, iCat, (long long)NB * LN * IDM / 4);
        split_wT_k<<<tgrid, blk256, 0, stream>>>(q_w, qCatT);
        split_wT_k<<<tgrid, blk256, 0, stream>>>(k_w, kCatT);
        transp_f32_f16<<<tgrid, blk256, 0, stream>>>(v_w, vT);
        transp_f32_f16<<<tgrid, blk256, 0, stream>>>(mlp_w, mlpT);

        // fused Q+K projection: B rows 0-1023 = q weight, 1024-2047 = k weight
        gemm256<6><<<dim3(8, 64), blk512, LDSB, stream>>>(
            iCat, L2048, 1024, qCatT + 1024, L2048,
            iCat, L2048, 2048, qCatT, L2048,
            Kcat, Qcat, NB * LN, 2048, 0, 0, 0, 0);
        gemm256<3><<<dim3(4, 64), blk512, LDSB, stream>>>(
            iCat, L2048, 1024, vT, L1024,
            nullptr, 0, 0, nullptr, 0,
            nullptr, VT, NB * LN, 1024, 0, 0, 0, 0);
        // iCat now dead; sc aliases it.

        for (int c = 0; c < 2; ++c) {
            const size_t coff = (size_t)c * 4 * LN * 2048;
            gemm256<2><<<dim3(8, 8, 4), blk512, LDSB, stream>>>(
                Qcat + coff, L2048, 1024, Kcat + coff + 1024, L2048,
                Qcat + coff, L2048, 2048, Kcat + coff, L2048,
                nullptr, sc, LN, LN,
                (long long)LN * 2048, (long long)LN * 2048, (long long)LN * LN, 0);
            // compact att into Kcat region of the SAME batches (just fully read)
            softmax_k<<<dim3(LN, 4), blk256, 0, stream>>>(
                sc, attA + (size_t)c * 4 * LN * LN, L2048, (long long)LN * LN);
        }
        // PV for all 8 batches in ONE dispatch: grid (4,8,8)=256 blocks, full device
        gemm256<4><<<dim3(4, 8, 8), blk512, LDSB, stream>>>(
            attA, L2048, 2048, VT, L2048,
            nullptr, 0, 0, nullptr, 0,
            i_in, ret, LN, IDM,
            (long long)LN * LN, (long long)IDM * LN, (long long)LN * IDM, (long long)LN * IDM);
        gemm256<5><<<dim3(4, 64), blk512, LDSB, stream>>>(
            ret, L1024, 1024, mlpT, L1024,
            nullptr, 0, 0, nullptr, 0,
            bias, out, NB * LN, 1024, 0, 0, 0, 0);
    } else {
        // -------- small path (~60 MiB), per batch --------
        _Float16* qCatT = (_Float16*)(ws);               // contiguous with kCatT
        _Float16* kCatT = (_Float16*)(ws + 4 * MiB);
        _Float16* vT    = (_Float16*)(ws + 8 * MiB);
        _Float16* mlpT  = (_Float16*)(ws + 10 * MiB);
        _Float16* iCat  = (_Float16*)(ws + 12 * MiB);
        _Float16* Qcat  = (_Float16*)(ws + 20 * MiB);
        _Float16* Kcat  = (_Float16*)(ws + 28 * MiB);
        _Float16* VTb   = (_Float16*)(ws + 36 * MiB);
        float*    sc    = (float*)(ws + 40 * MiB);
        _Float16* ret   = (_Float16*)(ws + 56 * MiB);

        split_wT_k<<<tgrid, blk256, 0, stream>>>(q_w, qCatT);
        split_wT_k<<<tgrid, blk256, 0, stream>>>(k_w, kCatT);
        transp_f32_f16<<<tgrid, blk256, 0, stream>>>(v_w, vT);
        transp_f32_f16<<<tgrid, blk256, 0, stream>>>(mlp_w, mlpT);

        for (int b = 0; b < NB; ++b) {
            const size_t boff = (size_t)b * LN * IDM;
            split_i_k<<<dim3(2048), blk256, 0, stream>>>(i_in + boff, iCat, (long long)LN * IDM / 4);
            gemm256<6><<<dim3(8, 8), blk512, LDSB, stream>>>(
                iCat, L2048, 1024, qCatT + 1024, L2048,
                iCat, L2048, 2048, qCatT, L2048,
                Kcat, Qcat, LN, 2048, 0, 0, 0, 0);
            gemm256<3><<<dim3(4, 8), blk512, LDSB, stream>>>(
                iCat, L2048, 1024, vT, L1024,
                nullptr, 0, 0, nullptr, 0,
                nullptr, VTb, LN, 1024, 0, 0, 0, 0);
            gemm256<2><<<dim3(8, 8), blk512, LDSB, stream>>>(
                Qcat, L2048, 1024, Kcat + 1024, L2048,
                Qcat, L2048, 2048, Kcat, L2048,
                nullptr, sc, LN, LN, 0, 0, 0, 0);
            softmax_k<<<dim3(LN, 1), blk256, 0, stream>>>(
                sc, (_Float16*)sc, L4096, 0);   // in-place, f16 rows at stride 4096
            gemm256<4><<<dim3(4, 8), blk512, LDSB, stream>>>(
                (const _Float16*)sc, L4096, 2048, VTb, L2048,
                nullptr, 0, 0, nullptr, 0,
                i_in + boff, ret, LN, IDM, 0, 0, 0, 0);
            gemm256<5><<<dim3(4, 8), blk512, LDSB, stream>>>(
                ret, L1024, 1024, mlpT, L1024,
                nullptr, 0, 0, nullptr, 0,
                bias, out + boff, LN, 1024, 0, 0, 0, 0);
        }
    }
}